// Round 1
// baseline (17.538 us; speedup 1.0000x reference)
//
#include <hip/hip_runtime.h>
#include <hip/hip_bf16.h>

// loss = sum_{i<n} (1 - prod_{j<len_i} (1 - x[i, y[i,j]])),  n = B/8.
// One 64-lane wave per row; shfl multiply-reduce; atomicAdd the row term.

__global__ void sample_loss_kernel(const float* __restrict__ x,
                                   const int* __restrict__ y,
                                   const int* __restrict__ lengths,
                                   float* __restrict__ out,
                                   int C, int L) {
    const int row  = blockIdx.x;
    const int lane = threadIdx.x;           // 0..63
    const int len  = lengths[row];          // 0..L-1
    const long long xbase = (long long)row * C;
    const long long ybase = (long long)row * L;

    float p = 1.0f;
    for (int j = lane; j < len; j += 64) {
        const int idx = y[ybase + j];
        p *= (1.0f - x[xbase + idx]);
    }
    // 64-lane multiply reduction (butterfly)
    #pragma unroll
    for (int off = 32; off >= 1; off >>= 1)
        p *= __shfl_xor(p, off, 64);

    if (lane == 0)
        atomicAdd(out, 1.0f - p);
}

extern "C" void kernel_launch(void* const* d_in, const int* in_sizes, int n_in,
                              void* d_out, int out_size, void* d_ws, size_t ws_size,
                              hipStream_t stream) {
    const float* x       = (const float*)d_in[0];
    const int*   y       = (const int*)d_in[1];
    const int*   lengths = (const int*)d_in[2];
    float*       out     = (float*)d_out;

    const int B = in_sizes[2];              // 4096
    const int L = in_sizes[1] / B;          // 200
    const int C = in_sizes[0] / B;          // 50000
    const int n = B / 8;                    // 512 rows actually used

    // d_out is poisoned once and never re-poisoned between timed replays:
    // zero it every launch (async memset is graph-capture safe).
    hipMemsetAsync(out, 0, sizeof(float) * out_size, stream);

    sample_loss_kernel<<<n, 64, 0, stream>>>(x, y, lengths, out, C, L);
}

// Round 2
// 11.295 us; speedup vs baseline: 1.5527x; 1.5527x over previous
//
#include <hip/hip_runtime.h>
#include <hip/hip_bf16.h>

// loss = sum_{i<n} (1 - prod_{j<len_i} (1 - x[i, y[i,j]])),  n = B/8 = 512.
//
// Kernel A: one block per row, one thread per position j (L=200 <= 256).
//   Every thread issues its y-load and x-gather unconditionally (y[i,j] is
//   always a valid column index), predicating only the multiplicand with
//   j < len. This gives exactly 2 dependent memory round trips per thread
//   and 8 waves/CU of latency hiding. Block-level product reduction
//   (wave shfl + LDS), then ws[row] = 1 - prod  (plain store, no init).
// Kernel B: one block sums the 512 partials and overwrites out[0]
//   (no memset dispatch, no atomics, deterministic order).

__global__ void __launch_bounds__(256)
row_term_kernel(const float* __restrict__ x,
                const int* __restrict__ y,
                const int* __restrict__ lengths,
                float* __restrict__ ws,
                int C, int L) {
    const int row = blockIdx.x;
    const int tid = threadIdx.x;            // 0..255
    const int len = lengths[row];

    float v = 1.0f;
    // L=200 <= blockDim (256): at most one element per thread; loop kept
    // for generality, executes once with j=tid.
    for (int j = tid; j < L; j += 256) {
        const int   idx = y[(long long)row * L + j];          // coalesced
        const float xv  = x[(long long)row * C + idx];        // gather (always valid)
        v *= (j < len) ? (1.0f - xv) : 1.0f;
    }

    // wave-level product reduction (64 lanes)
    #pragma unroll
    for (int off = 32; off >= 1; off >>= 1)
        v *= __shfl_xor(v, off, 64);

    __shared__ float wprod[4];
    const int wave = tid >> 6;
    if ((tid & 63) == 0) wprod[wave] = v;
    __syncthreads();
    if (tid == 0)
        ws[row] = 1.0f - (wprod[0] * wprod[1] * wprod[2] * wprod[3]);
}

__global__ void __launch_bounds__(512)
reduce_kernel(const float* __restrict__ ws, float* __restrict__ out, int n) {
    const int tid = threadIdx.x;            // 0..511, n == 512
    float s = (tid < n) ? ws[tid] : 0.0f;
    #pragma unroll
    for (int off = 32; off >= 1; off >>= 1)
        s += __shfl_xor(s, off, 64);

    __shared__ float wsum[8];
    const int wave = tid >> 6;
    if ((tid & 63) == 0) wsum[wave] = s;
    __syncthreads();
    if (tid == 0) {
        float t = 0.0f;
        #pragma unroll
        for (int w = 0; w < 8; ++w) t += wsum[w];
        out[0] = t;                          // overwrite: no memset needed
    }
}

extern "C" void kernel_launch(void* const* d_in, const int* in_sizes, int n_in,
                              void* d_out, int out_size, void* d_ws, size_t ws_size,
                              hipStream_t stream) {
    const float* x       = (const float*)d_in[0];
    const int*   y       = (const int*)d_in[1];
    const int*   lengths = (const int*)d_in[2];
    float*       out     = (float*)d_out;
    float*       ws      = (float*)d_ws;

    const int B = in_sizes[2];              // 4096
    const int L = in_sizes[1] / B;          // 200
    const int C = in_sizes[0] / B;          // 50000
    const int n = B / 8;                    // 512 rows used

    row_term_kernel<<<n, 256, 0, stream>>>(x, y, lengths, ws, C, L);
    reduce_kernel<<<1, 512, 0, stream>>>(ws, out, n);
}